// Round 3
// baseline (265.283 us; speedup 1.0000x reference)
//
#include <hip/hip_runtime.h>

#define B_SZ 512
#define V_SZ 1024
#define K_SZ 64
#define C_SZ 2048
#define A_SZ 128

#define LOG2E 1.4426950408889634f

// ---------------------------------------------------------------------------
// Kernel 1: alpha = exp(xs@Wa+ba), beta = exp(xs@Wb+bb),
//           new_kappa = prev_kappa + exp(xs@Wk+bk)
// 256 blocks x 256 threads, 2 batch rows per block.
// Thread (k = tid&63, vc = tid>>6): partial dot over V-chunk of 256 for all
// 3 matrices x 2 rows; LDS tree-reduce the 4 V-chunks. W reads are 256B
// coalesced per wave and L2-resident (786KB total).
// ---------------------------------------------------------------------------
__global__ __launch_bounds__(256) void gw_abk(
    const float* __restrict__ x,
    const float* __restrict__ prev_kappa,
    const float* __restrict__ Wa, const float* __restrict__ ba,
    const float* __restrict__ Wb, const float* __restrict__ bb,
    const float* __restrict__ Wk, const float* __restrict__ bk,
    float* __restrict__ ws_alpha, float* __restrict__ ws_beta,
    float* __restrict__ ws_kappa, float* __restrict__ out_kappa) {
  __shared__ float xs[2][V_SZ];
  __shared__ float part[3][2][4][K_SZ];   // [mat][row][vchunk][k] = 6KB

  const int tid = threadIdx.x;
  const int b0 = blockIdx.x * 2;

  // stage 2 rows of x (8KB) as float4
  {
    const float4* xsrc = (const float4*)(x + (size_t)b0 * V_SZ);
    float4* xdst = (float4*)&xs[0][0];
    xdst[tid] = xsrc[tid];
    xdst[tid + 256] = xsrc[tid + 256];
  }
  __syncthreads();

  const int k = tid & 63;
  const int vc = tid >> 6;
  const int v0 = vc * 256;

  float a00 = 0.f, a01 = 0.f, a10 = 0.f, a11 = 0.f, a20 = 0.f, a21 = 0.f;
#pragma unroll 8
  for (int v = v0; v < v0 + 256; ++v) {
    float x0 = xs[0][v];               // LDS broadcast (wave-uniform v)
    float x1 = xs[1][v];
    float wa = Wa[v * K_SZ + k];       // 256B coalesced per wave
    float wb = Wb[v * K_SZ + k];
    float wk = Wk[v * K_SZ + k];
    a00 = fmaf(x0, wa, a00); a01 = fmaf(x1, wa, a01);
    a10 = fmaf(x0, wb, a10); a11 = fmaf(x1, wb, a11);
    a20 = fmaf(x0, wk, a20); a21 = fmaf(x1, wk, a21);
  }

  part[0][0][vc][k] = a00; part[0][1][vc][k] = a01;
  part[1][0][vc][k] = a10; part[1][1][vc][k] = a11;
  part[2][0][vc][k] = a20; part[2][1][vc][k] = a21;
  __syncthreads();

  // 384 work items (3 mats x 2 rows x 64 k) on 256 threads: strided loop.
  for (int i = tid; i < 384; i += 256) {
    const int m = i >> 7;            // 0=alpha, 1=beta, 2=kappa
    const int r = (i >> 6) & 1;
    const int kk = i & 63;
    float s = part[m][r][0][kk] + part[m][r][1][kk] +
              part[m][r][2][kk] + part[m][r][3][kk];
    const float bias = ((m == 0) ? ba : (m == 1) ? bb : bk)[kk];
    const float e = expf(s + bias);
    const int idx = (b0 + r) * K_SZ + kk;
    if (m == 0) {
      ws_alpha[idx] = e;
    } else if (m == 1) {
      ws_beta[idx] = e;
    } else {
      float nk = prev_kappa[idx] + e;
      ws_kappa[idx] = nk;
      out_kappa[idx] = nk;
    }
  }
}

// ---------------------------------------------------------------------------
// Kernel 2: one block (512 threads) per batch row.
//  1) load (alpha, beta, kappa), compute conservative cutoff CL: for c >= CL
//     every Gaussian term is <= 2^-150 -> phi[c] == 0 (below fp32 denormal
//     noise, vs absmax threshold ~6.9).
//  2) phi[c] for c < CL (exact), zeros beyond; write phi output.
//  3) window = phi[0:CL) @ text[0:CL)  -- reads only CL rows of text.
// ---------------------------------------------------------------------------
__global__ __launch_bounds__(512) void gw_phi_window(
    const float* __restrict__ text,
    const float* __restrict__ ws_alpha, const float* __restrict__ ws_beta,
    const float* __restrict__ ws_kappa,
    float* __restrict__ out_phi, float* __restrict__ out_window) {
  __shared__ float al[K_SZ];
  __shared__ float bn[K_SZ];     // -log2(e) * beta  (exp2 scale)
  __shared__ float kap[K_SZ];
  __shared__ float bnd[K_SZ];
  __shared__ int cl_s;
  __shared__ float phi_s[C_SZ];
  __shared__ float4 red[16][32];

  const int tid = threadIdx.x;
  const int b = blockIdx.x;

  if (tid < K_SZ) {
    float a  = ws_alpha[b * K_SZ + tid];
    float be = ws_beta[b * K_SZ + tid];
    float kp = ws_kappa[b * K_SZ + tid];
    al[tid] = a;
    bn[tid] = -LOG2E * be;
    kap[tid] = kp;
    // solve LOG2E*be*d^2 >= 150 + max(0, log2(a))  ->  term <= 2^-150
    float num = 150.f + fmaxf(0.f, log2f(a));
    bnd[tid] = kp + sqrtf(num / (LOG2E * be));
  }
  __syncthreads();

  if (tid == 0) {
    float m = 0.f;
    for (int i = 0; i < K_SZ; ++i) m = fmaxf(m, bnd[i]);
    m = fminf(m, (float)C_SZ);        // also sanitizes inf -> full compute
    int cl = (int)m + 1;
    cl = (cl + 15) & ~15;             // multiple of 16 for the window loop
    if (cl > C_SZ) cl = C_SZ;
    cl_s = cl;
  }
  __syncthreads();
  const int CL = cl_s;

  // ---- phi for c < CL ----
  for (int c = tid; c < CL; c += 512) {
    float cf = (float)c;
    float s = 0.f;
#pragma unroll
    for (int k = 0; k < K_SZ; ++k) {
      float d = kap[k] - cf;
      s += al[k] * exp2f(bn[k] * d * d);
    }
    phi_s[c] = s;
    out_phi[(size_t)b * C_SZ + c] = s;
  }
  // ---- exact zeros for c >= CL ----
  {
    float4 z = make_float4(0.f, 0.f, 0.f, 0.f);
    float4* po = (float4*)(out_phi + (size_t)b * C_SZ);
    for (int i = (CL >> 2) + tid; i < C_SZ / 4; i += 512) po[i] = z;
  }
  __syncthreads();

  // ---- window over [0, CL) rows of text ----
  const float4* __restrict__ t4 =
      (const float4*)(text + (size_t)b * C_SZ * A_SZ);
  const int a4 = tid & 31;   // float4 column (covers A=128)
  const int cr = tid >> 5;   // 16 parallel c-rows

  float4 acc = make_float4(0.f, 0.f, 0.f, 0.f);
  for (int cc = cr; cc < CL; cc += 16) {
    float p = phi_s[cc];
    float4 t = t4[cc * 32 + a4];       // coalesced 512B per row
    acc.x = fmaf(p, t.x, acc.x);
    acc.y = fmaf(p, t.y, acc.y);
    acc.z = fmaf(p, t.z, acc.z);
    acc.w = fmaf(p, t.w, acc.w);
  }

  red[cr][a4] = acc;
  __syncthreads();

  if (tid < 32) {
    float4 w = red[0][tid];
#pragma unroll
    for (int i = 1; i < 16; ++i) {
      float4 r = red[i][tid];
      w.x += r.x; w.y += r.y; w.z += r.z; w.w += r.w;
    }
    ((float4*)(out_window + (size_t)b * A_SZ))[tid] = w;
  }
}

extern "C" void kernel_launch(void* const* d_in, const int* in_sizes, int n_in,
                              void* d_out, int out_size, void* d_ws, size_t ws_size,
                              hipStream_t stream) {
  const float* x    = (const float*)d_in[0];
  const float* text = (const float*)d_in[1];
  const float* pk   = (const float*)d_in[2];
  const float* Wa   = (const float*)d_in[3];
  const float* ba   = (const float*)d_in[4];
  const float* Wb   = (const float*)d_in[5];
  const float* bb   = (const float*)d_in[6];
  const float* Wk   = (const float*)d_in[7];
  const float* bk   = (const float*)d_in[8];

  float* out        = (float*)d_out;
  float* out_phi    = out;                              // B*C
  float* out_kappa  = out + (size_t)B_SZ * C_SZ;        // B*K
  float* out_win    = out_kappa + (size_t)B_SZ * K_SZ;  // B*A

  float* ws         = (float*)d_ws;
  float* ws_alpha   = ws;
  float* ws_beta    = ws + (size_t)B_SZ * K_SZ;
  float* ws_kappa   = ws + (size_t)2 * B_SZ * K_SZ;

  gw_abk<<<B_SZ / 2, 256, 0, stream>>>(x, pk, Wa, ba, Wb, bb, Wk, bk,
                                       ws_alpha, ws_beta, ws_kappa, out_kappa);
  gw_phi_window<<<B_SZ, 512, 0, stream>>>(text, ws_alpha, ws_beta, ws_kappa,
                                          out_phi, out_win);
}

// Round 4
// 28.248 us; speedup vs baseline: 9.3914x; 9.3914x over previous
//
#include <hip/hip_runtime.h>

#define B_SZ 512
#define V_SZ 1024
#define K_SZ 64
#define C_SZ 2048
#define A_SZ 128

#define LOG2E 1.4426950408889634f

// ---------------------------------------------------------------------------
// Kernel 1: alpha = exp(xs@Wa+ba), beta = exp(xs@Wb+bb),
//           new_kappa = prev_kappa + exp(xs@Wk+bk)
// 512 blocks (1 batch row each) x 192 threads (3 waves).
// Wave 0 -> alpha, wave 1 -> beta, wave 2 -> kappa; lane = k.
// x row staged in LDS (broadcast reads); W reads 256B-coalesced, L2-resident.
// ---------------------------------------------------------------------------
__global__ __launch_bounds__(192) void gw_abk(
    const float* __restrict__ x,
    const float* __restrict__ prev_kappa,
    const float* __restrict__ Wa, const float* __restrict__ ba,
    const float* __restrict__ Wb, const float* __restrict__ bb,
    const float* __restrict__ Wk, const float* __restrict__ bk,
    float* __restrict__ ws_alpha, float* __restrict__ ws_beta,
    float* __restrict__ ws_kappa, float* __restrict__ out_kappa) {
  __shared__ float xs[V_SZ];
  const int tid = threadIdx.x;
  const int b = blockIdx.x;

  {
    const float4* xsrc = (const float4*)(x + (size_t)b * V_SZ);
    float4* xdst = (float4*)xs;
    for (int i = tid; i < V_SZ / 4; i += 192) xdst[i] = xsrc[i];
  }
  __syncthreads();

  const int which = tid >> 6;   // 0=alpha wave, 1=beta wave, 2=kappa wave
  const int k = tid & 63;
  const float* __restrict__ W = (which == 0) ? Wa : (which == 1) ? Wb : Wk;
  const float bias = ((which == 0) ? ba : (which == 1) ? bb : bk)[k];

  float acc = 0.f;
#pragma unroll 16
  for (int v = 0; v < V_SZ; ++v) {
    acc = fmaf(xs[v], W[v * K_SZ + k], acc);   // 256B coalesced per wave
  }

  const float e = expf(acc + bias);
  const int idx = b * K_SZ + k;
  if (which == 0) {
    ws_alpha[idx] = e;
  } else if (which == 1) {
    ws_beta[idx] = e;
  } else {
    float nk = prev_kappa[idx] + e;
    ws_kappa[idx] = nk;
    out_kappa[idx] = nk;
  }
}

// ---------------------------------------------------------------------------
// Kernel 2 (verbatim from passing R3): one block (512 threads) per batch row.
//  1) conservative cutoff CL: for c >= CL every Gaussian term <= 2^-150
//     -> phi[c] == 0 exactly (vs absmax threshold ~6.9).
//  2) phi[c] for c < CL (exact), zeros beyond; write phi output.
//  3) window = phi[0:CL) @ text[0:CL)  -- reads only CL rows of text.
// ---------------------------------------------------------------------------
__global__ __launch_bounds__(512) void gw_phi_window(
    const float* __restrict__ text,
    const float* __restrict__ ws_alpha, const float* __restrict__ ws_beta,
    const float* __restrict__ ws_kappa,
    float* __restrict__ out_phi, float* __restrict__ out_window) {
  __shared__ float al[K_SZ];
  __shared__ float bn[K_SZ];     // -log2(e) * beta  (exp2 scale)
  __shared__ float kap[K_SZ];
  __shared__ float bnd[K_SZ];
  __shared__ int cl_s;
  __shared__ float phi_s[C_SZ];
  __shared__ float4 red[16][32];

  const int tid = threadIdx.x;
  const int b = blockIdx.x;

  if (tid < K_SZ) {
    float a  = ws_alpha[b * K_SZ + tid];
    float be = ws_beta[b * K_SZ + tid];
    float kp = ws_kappa[b * K_SZ + tid];
    al[tid] = a;
    bn[tid] = -LOG2E * be;
    kap[tid] = kp;
    // solve LOG2E*be*d^2 >= 150 + max(0, log2(a))  ->  term <= 2^-150
    float num = 150.f + fmaxf(0.f, log2f(a));
    bnd[tid] = kp + sqrtf(num / (LOG2E * be));
  }
  __syncthreads();

  if (tid == 0) {
    float m = 0.f;
    for (int i = 0; i < K_SZ; ++i) m = fmaxf(m, bnd[i]);
    m = fminf(m, (float)C_SZ);        // also sanitizes inf -> full compute
    int cl = (int)m + 1;
    cl = (cl + 15) & ~15;             // multiple of 16 for the window loop
    if (cl > C_SZ) cl = C_SZ;
    cl_s = cl;
  }
  __syncthreads();
  const int CL = cl_s;

  // ---- phi for c < CL ----
  for (int c = tid; c < CL; c += 512) {
    float cf = (float)c;
    float s = 0.f;
#pragma unroll
    for (int k = 0; k < K_SZ; ++k) {
      float d = kap[k] - cf;
      s += al[k] * exp2f(bn[k] * d * d);
    }
    phi_s[c] = s;
    out_phi[(size_t)b * C_SZ + c] = s;
  }
  // ---- exact zeros for c >= CL ----
  {
    float4 z = make_float4(0.f, 0.f, 0.f, 0.f);
    float4* po = (float4*)(out_phi + (size_t)b * C_SZ);
    for (int i = (CL >> 2) + tid; i < C_SZ / 4; i += 512) po[i] = z;
  }
  __syncthreads();

  // ---- window over [0, CL) rows of text ----
  const float4* __restrict__ t4 =
      (const float4*)(text + (size_t)b * C_SZ * A_SZ);
  const int a4 = tid & 31;   // float4 column (covers A=128)
  const int cr = tid >> 5;   // 16 parallel c-rows

  float4 acc = make_float4(0.f, 0.f, 0.f, 0.f);
  for (int cc = cr; cc < CL; cc += 16) {
    float p = phi_s[cc];
    float4 t = t4[cc * 32 + a4];       // coalesced 512B per row
    acc.x = fmaf(p, t.x, acc.x);
    acc.y = fmaf(p, t.y, acc.y);
    acc.z = fmaf(p, t.z, acc.z);
    acc.w = fmaf(p, t.w, acc.w);
  }

  red[cr][a4] = acc;
  __syncthreads();

  if (tid < 32) {
    float4 w = red[0][tid];
#pragma unroll
    for (int i = 1; i < 16; ++i) {
      float4 r = red[i][tid];
      w.x += r.x; w.y += r.y; w.z += r.z; w.w += r.w;
    }
    ((float4*)(out_window + (size_t)b * A_SZ))[tid] = w;
  }
}

extern "C" void kernel_launch(void* const* d_in, const int* in_sizes, int n_in,
                              void* d_out, int out_size, void* d_ws, size_t ws_size,
                              hipStream_t stream) {
  const float* x    = (const float*)d_in[0];
  const float* text = (const float*)d_in[1];
  const float* pk   = (const float*)d_in[2];
  const float* Wa   = (const float*)d_in[3];
  const float* ba   = (const float*)d_in[4];
  const float* Wb   = (const float*)d_in[5];
  const float* bb   = (const float*)d_in[6];
  const float* Wk   = (const float*)d_in[7];
  const float* bk   = (const float*)d_in[8];

  float* out        = (float*)d_out;
  float* out_phi    = out;                              // B*C
  float* out_kappa  = out + (size_t)B_SZ * C_SZ;        // B*K
  float* out_win    = out_kappa + (size_t)B_SZ * K_SZ;  // B*A

  float* ws         = (float*)d_ws;
  float* ws_alpha   = ws;
  float* ws_beta    = ws + (size_t)B_SZ * K_SZ;
  float* ws_kappa   = ws + (size_t)2 * B_SZ * K_SZ;

  gw_abk<<<B_SZ, 192, 0, stream>>>(x, pk, Wa, ba, Wb, bb, Wk, bk,
                                   ws_alpha, ws_beta, ws_kappa, out_kappa);
  gw_phi_window<<<B_SZ, 512, 0, stream>>>(text, ws_alpha, ws_beta, ws_kappa,
                                          out_phi, out_win);
}